// Round 3
// baseline (296426.221 us; speedup 1.0000x reference)
//
#include <hip/hip_runtime.h>
#include <math.h>

#define B_    32
#define S_    512
#define EMB_  512
#define HID_  1024
#define LAB_  64
#define M_    (B_ * S_)

// ---------------------------------------------------------------------------
// R12 exchange: single-hop tagged data (R9 protocol) with an XCD-LOCAL fast
// path. One u64 per (batch,neuron) = (tag<<32)|bits, layout [2][B_][HID_]
// (512 KB in d_out) + 256 startup words.
//
// R9 (agent atomics everywhere) = 7900 cyc/step: agent scope bypasses the
// XCD L2 by definition (IF$ is the agent coherence point) -> every poll is
// a fabric RT. R11 (flag-gating) = 12100 cyc/step: extra hops cost more
// than poll traffic saved. Single-hop is latency-optimal; the remaining
// lever is WHERE the exchange lives.
//
// Fast path (group verified XCD-local at runtime via HW_REG_XCC_ID):
//   producer: plain global_store_dwordx2 (L1 is write-through -> lands in
//             the shared per-XCD L2)  PLUS an identical agent-scope store
//             (IF$ copy) -> word visible no matter which level serves the
//             consumer's load. Same value, benign race.
//   consumer: global_load_dwordx2 sc0 (bypass per-CU L1, served by L2,
//             ~200cy) in a 4-load/1-waitcnt sweep. Tag self-validates.
//   escape:   >64k sweeps (only if sc0 semantics differ) -> WG permanently
//             drops to the agent path. No deadlock branch exists.
// Fallback path: R9 code verbatim (correct for any WG->XCD mapping).
//
// Slot-reuse safety (depth 2, unchanged): publishing tag t implies this WG
// consumed all of t-1, which implies every group member published t-1,
// which implies every member finished reading slot t-2 before overwrite.
// Tags: layer0 1..512, layer1 513..1024; logits/0/garbage never match.
// ---------------------------------------------------------------------------
#define EX_SLOT (B_ * HID_)          // u64 words per data slot (2 slots)
#define SX_BASE (2 * EX_SLOT)        // u64 offset of 256 startup words

__device__ __forceinline__ unsigned long long aload64(const unsigned long long* p) {
    return __hip_atomic_load((unsigned long long*)p, __ATOMIC_RELAXED,
                             __HIP_MEMORY_SCOPE_AGENT);
}
__device__ __forceinline__ void astore64(unsigned long long* p, unsigned long long v) {
    __hip_atomic_store(p, v, __ATOMIC_RELAXED, __HIP_MEMORY_SCOPE_AGENT);
}
// plain store: write-through L1 -> this XCD's L2 (fast path data copy)
__device__ __forceinline__ void store64_l2(unsigned long long* p, unsigned long long v) {
    asm volatile("global_store_dwordx2 %0, %1, off" :: "v"(p), "v"(v) : "memory");
}

// ---------------------------------------------------------------------------
// fp32 tiled GEMM, BM=128, BN=64, BK=16, 256 threads, 8x4/thread (measured
// ~0.79 ms total across the three projections). Optional row-gather on A.
// ---------------------------------------------------------------------------
__global__ __launch_bounds__(256) void gemm_bias(
    const float* __restrict__ A, const int* __restrict__ tokens,
    const float* __restrict__ W, const float* __restrict__ bias,
    const float* __restrict__ bias2, float* __restrict__ C,
    int M, int K, int N)
{
    __shared__ float As[128][17];
    __shared__ float Ws[64][17];

    const int tid = threadIdx.x;
    const int tx  = tid & 15;
    const int ty  = tid >> 4;
    const int n0  = blockIdx.x * 64;
    const int m0  = blockIdx.y * 128;

    const int lr  = tid >> 2;
    const int lk  = (tid & 3) << 2;

    const int ar0 = tokens ? tokens[m0 + lr]      : (m0 + lr);
    const int ar1 = tokens ? tokens[m0 + 64 + lr] : (m0 + 64 + lr);
    const float* __restrict__ arow0 = A + (size_t)ar0 * K;
    const float* __restrict__ arow1 = A + (size_t)ar1 * K;
    const float* __restrict__ wrow  = W + (size_t)(n0 + lr) * K;

    float bs[4];
#pragma unroll
    for (int j = 0; j < 4; ++j) {
        int n = n0 + tx * 4 + j;
        bs[j] = bias[n] + (bias2 ? bias2[n] : 0.0f);
    }

    float acc[8][4] = {};

    for (int k0 = 0; k0 < K; k0 += 16) {
        const float4 a0 = *(const float4*)(arow0 + k0 + lk);
        const float4 a1 = *(const float4*)(arow1 + k0 + lk);
        const float4 wv = *(const float4*)(wrow  + k0 + lk);
        __syncthreads();
        As[lr][lk + 0] = a0.x; As[lr][lk + 1] = a0.y;
        As[lr][lk + 2] = a0.z; As[lr][lk + 3] = a0.w;
        As[64 + lr][lk + 0] = a1.x; As[64 + lr][lk + 1] = a1.y;
        As[64 + lr][lk + 2] = a1.z; As[64 + lr][lk + 3] = a1.w;
        Ws[lr][lk + 0] = wv.x; Ws[lr][lk + 1] = wv.y;
        Ws[lr][lk + 2] = wv.z; Ws[lr][lk + 3] = wv.w;
        __syncthreads();

#pragma unroll
        for (int kk = 0; kk < 16; ++kk) {
            float b[4], a[8];
#pragma unroll
            for (int j = 0; j < 4; ++j) b[j] = Ws[tx * 4 + j][kk];
#pragma unroll
            for (int i = 0; i < 8; ++i) a[i] = As[ty * 8 + i][kk];
#pragma unroll
            for (int i = 0; i < 8; ++i)
#pragma unroll
                for (int j = 0; j < 4; ++j)
                    acc[i][j] += a[i] * b[j];
        }
    }

#pragma unroll
    for (int i = 0; i < 8; ++i) {
        const int m = m0 + ty * 8 + i;
        float4 v;
        v.x = acc[i][0] + bs[0];
        v.y = acc[i][1] + bs[1];
        v.z = acc[i][2] + bs[2];
        v.w = acc[i][3] + bs[3];
        *(float4*)(C + (size_t)m * N + n0 + tx * 4) = v;
    }
}

// ---------------------------------------------------------------------------
// Weight-stationary persistent scan, R12: XCD-local L2 exchange fast path.
// 256 WGs x 512 threads, 1 WG/CU. Group = wg&15 (16 groups x 2 batches).
// Slice s = wg>>4: 64 neurons. Weights in registers: 8 neurons x 16
// strided k = 128 VGPRs. LDS h: float2[2][1024] double-buffered -> ONE
// barrier per step. Safety: a thread's reads of buf[(t-1)&1] precede
// (program order) its staging of buf[t&1], which precedes barrier_t; any
// thread writes buf[(t+1)&1] = buf[(t-1)&1] only after passing barrier_t.
// 16-acc halving-tree reduction: lane p holds out(p&15) at the end.
// ---------------------------------------------------------------------------
__global__ __launch_bounds__(512, 2) void rnn_scan_tag(
    const float* __restrict__ Whh,          // [H][H] row-major
    float* __restrict__ x,                  // [B,S,H]  xp in, h out (in place)
    unsigned long long* __restrict__ ex,    // data + startup exchange (d_out)
    unsigned tag0)                          // 1 (layer0) / 513 (layer1)
{
    extern __shared__ float smem[];
    float2* hb2 = (float2*)smem;            // [2][1024] float2 = 16 KB
    volatile int* gflag = (volatile int*)(smem + 4096);  // past hb2

    const int wg  = blockIdx.x;
    const int bg  = wg & 15;         // batch group (2 batches)
    const int s   = wg >> 4;         // slice 0..15 (64 neurons)
    const int tid = threadIdx.x;     // 0..511
    const int j8  = tid >> 6;        // wave 0..7 -> neurons s*64 + j8*8 ..+7
    const int kg  = tid & 63;        // lane; k = kg + 64q
    const int b0  = bg * 2;

    // ---- startup: verify this group is XCD-local (ground truth from HW) ----
    int gfast;
    {
        unsigned myxcd;
        asm volatile("s_getreg_b32 %0, hwreg(HW_REG_XCC_ID)" : "=s"(myxcd));
        myxcd &= 0xfu;
        unsigned long long* sx = ex + SX_BASE;
        if (tid == 0)
            astore64(sx + wg, ((unsigned long long)tag0 << 32) |
                              (unsigned long long)myxcd);
        if (tid < 64) {                      // wave 0 polls its 16 members
            const int mem = bg + 16 * (tid & 15);
            const bool need = (tid < 16);
            unsigned long long vv = 0;
            do {
                if (need) vv = aload64(sx + mem);
            } while (!__all(!need || (unsigned)(vv >> 32) == tag0));
            const int same = __all(!need || (unsigned)vv == myxcd);
            if (tid == 0) *gflag = same;
        }
        __syncthreads();
        gfast = *gflag;
    }

    // weights: 8 neurons x 16 strided k = 128 VGPRs (lane-coalesced loads)
    float wreg[8][16];
    {
        const float* wb = Whh + (size_t)(s * 64 + j8 * 8) * HID_ + kg;
#pragma unroll
        for (int i = 0; i < 8; ++i)
#pragma unroll
            for (int q = 0; q < 16; ++q)
                wreg[i][q] = wb[(size_t)i * HID_ + q * 64];
    }

    const int oi = (kg >> 1) & 7, ob = kg & 1;     // lane's output (kg<16)
    const int ok = s * 64 + j8 * 8 + oi;           // neuron index

    // incremental xp/h pointer (kg<16 lanes only)
    float* px = x + (size_t)(b0 + ob) * S_ * HID_ + ok;

    for (int t = 0; t < S_; ++t) {
        float2* cur = hb2 + (size_t)(t & 1) * HID_;

        // ---- xp prefetch: independent of h, overlaps the poll ----
        float xpv = 0.f;
        if (kg < 16) xpv = *px;

        // ---- stage h_{t-1} ----
        if (t > 0) {
            const unsigned wtag = tag0 + (unsigned)(t - 1);
            const unsigned long long* exs = ex + (size_t)((t - 1) & 1) * EX_SLOT;
            bool staged = false;

            if (gfast) {
                // L2-local sweep: 4 sc0 loads (bypass L1, hit XCD L2),
                // one RT per sweep. Tag self-validates; stale reads re-poll.
                const unsigned long long* p00 = exs + (size_t)b0 * HID_ + tid;
                const unsigned long long* p01 = p00 + HID_;
                const unsigned long long* p10 = p00 + 512;
                const unsigned long long* p11 = p01 + 512;
                unsigned long long w00, w01, w10, w11;
                int spins = 0;
                for (;;) {
                    asm volatile(
                        "global_load_dwordx2 %0, %4, off sc0\n\t"
                        "global_load_dwordx2 %1, %5, off sc0\n\t"
                        "global_load_dwordx2 %2, %6, off sc0\n\t"
                        "global_load_dwordx2 %3, %7, off sc0\n\t"
                        "s_waitcnt vmcnt(0)"
                        : "=&v"(w00), "=&v"(w01), "=&v"(w10), "=&v"(w11)
                        : "v"(p00), "v"(p01), "v"(p10), "v"(p11)
                        : "memory");
                    if ((unsigned)(w00 >> 32) == wtag &&
                        (unsigned)(w01 >> 32) == wtag &&
                        (unsigned)(w10 >> 32) == wtag &&
                        (unsigned)(w11 >> 32) == wtag) {
                        float2 v0, v1;
                        v0.x = __uint_as_float((unsigned)w00);
                        v0.y = __uint_as_float((unsigned)w01);
                        v1.x = __uint_as_float((unsigned)w10);
                        v1.y = __uint_as_float((unsigned)w11);
                        cur[tid]       = v0;
                        cur[tid + 512] = v1;
                        staged = true;
                        break;
                    }
                    // semantics escape: only reachable if sc0 can't see the
                    // plain-store copy; IF$ copy (double-publish) guarantees
                    // the agent path below makes progress.
                    if (++spins > (1 << 16)) { gfast = 0; break; }
                }
            }
            if (!staged) {
                // agent path (R9 verbatim): merged 4-word tagged poll
                unsigned long long w[2][2];      // [m-chunk][batch]
                unsigned pend = 0xfu;
                do {
#pragma unroll
                    for (int c = 0; c < 2; ++c)
#pragma unroll
                        for (int j = 0; j < 2; ++j) {
                            const unsigned bit = 1u << (c * 2 + j);
                            if (pend & bit) {
                                unsigned long long u = aload64(
                                    exs + (size_t)(b0 + j) * HID_ + tid + 512 * c);
                                if ((unsigned)(u >> 32) == wtag) {
                                    w[c][j] = u;
                                    pend &= ~bit;
                                }
                            }
                        }
                } while (pend);
#pragma unroll
                for (int c = 0; c < 2; ++c) {
                    float2 v;
                    v.x = __uint_as_float((unsigned)w[c][0]);
                    v.y = __uint_as_float((unsigned)w[c][1]);
                    cur[tid + 512 * c] = v;       // contiguous b64
                }
            }
        } else {
            cur[tid]       = make_float2(0.f, 0.f);
            cur[tid + 512] = make_float2(0.f, 0.f);
        }
        __syncthreads();   // the ONE barrier: staging done -> compute reads

        // ---- partials: v[a], a = i*2+b, over 16 strided k ----
        float v[16] = {};
#pragma unroll
        for (int q = 0; q < 16; ++q) {
            const float2 hv = cur[kg + 64 * q];    // lane-contig b64: free
#pragma unroll
            for (int i = 0; i < 8; ++i) {
                const float w = wreg[i][q];
                v[i * 2 + 0] += w * hv.x;
                v[i * 2 + 1] += w * hv.y;
            }
        }

        // ---- halving-tree reduction: 15+2 shfls fold 16 accs -> 1 ----
#pragma unroll
        for (int st = 0; st < 4; ++st) {
            const int m  = 1 << st;
            const int nh = 8 >> st;
            const bool hi = (kg & m) != 0;
#pragma unroll
            for (int j = 0; j < 8; ++j) {
                if (j < nh) {
                    const float a0 = v[2 * j], a1 = v[2 * j + 1];
                    const float got = __shfl_xor(hi ? a0 : a1, m, 64);
                    v[j] = (hi ? a1 : a0) + got;
                }
            }
        }
        v[0] += __shfl_xor(v[0], 16, 64);
        v[0] += __shfl_xor(v[0], 32, 64);
        // lane p now holds out(p & 15), a = i*2+b

        // ---- publish: single-hop tagged word per (batch, neuron) ----
        if (kg < 16) {
            const float hv = tanhf(xpv + v[0]);
            const unsigned long long u =
                ((unsigned long long)(tag0 + (unsigned)t) << 32) |
                (unsigned long long)__float_as_uint(hv);
            unsigned long long* pp = ex + (size_t)(t & 1) * EX_SLOT
                                        + (size_t)(b0 + ob) * HID_ + ok;
            if (gfast) {
                store64_l2(pp, u);   // L2 copy (fast consumer visibility)
                astore64(pp, u);     // IF$ copy (escape-path guarantee)
            } else {
                astore64(pp, u);
            }
            *px = hv;                               // for the next-layer GEMM
            px += HID_;
        }
        // no trailing barrier: double-buffered hb2 (see header comment)
    }
}

__global__ __launch_bounds__(256) void copy4(
    const float4* __restrict__ src, float4* __restrict__ dst, int n4)
{
    const int i = blockIdx.x * 256 + threadIdx.x;
    if (i < n4) dst[i] = src[i];
}

extern "C" void kernel_launch(void* const* d_in, const int* in_sizes, int n_in,
                              void* d_out, int out_size, void* d_ws, size_t ws_size,
                              hipStream_t stream)
{
    const int*   tokens = (const int*)  d_in[0];
    const float* emb    = (const float*)d_in[1];
    const float* W_ih0  = (const float*)d_in[2];
    const float* W_hh0  = (const float*)d_in[3];
    const float* b_ih0  = (const float*)d_in[4];
    const float* b_hh0  = (const float*)d_in[5];
    const float* W_ih1  = (const float*)d_in[6];
    const float* W_hh1  = (const float*)d_in[7];
    const float* b_ih1  = (const float*)d_in[8];
    const float* b_hh1  = (const float*)d_in[9];
    const float* W_out  = (const float*)d_in[10];
    const float* b_out  = (const float*)d_in[11];
    float* out = (float*)d_out;

    const size_t BUF = (size_t)B_ * S_ * HID_;   // 64 MiB
    float* buf  = (float*)d_ws;
    float* buf1 = buf + BUF;                     // only if ws_size permits
    float* tmp  = (float*)d_out;                 // chunk bounce (fallback)
    unsigned long long* ex = (unsigned long long*)d_out;  // 514 KB exchange

    const int two_buf = (ws_size >= 2 * BUF * sizeof(float));  // constant/call

    // 96 KB dynamic LDS -> exactly 1 WG/CU (256 WGs co-resident on 256 CUs)
    const size_t scan_lds = 98304;
    hipFuncSetAttribute((const void*)rnn_scan_tag,
                        hipFuncAttributeMaxDynamicSharedMemorySize, (int)scan_lds);

    // 1) xp0 = gather(emb,tokens) @ W_ih0^T + b_ih0 + b_hh0  -> buf
    gemm_bias<<<dim3(HID_ / 64, M_ / 128), 256, 0, stream>>>(
        emb, tokens, W_ih0, b_ih0, b_hh0, buf, M_, EMB_, HID_);

    // 2) layer-0 scan (in place on buf; tags 1..512)
    rnn_scan_tag<<<256, 512, scan_lds, stream>>>(W_hh0, buf, ex, 1u);

    float* l1buf;
    if (two_buf) {
        // 3a) full-grid xp1 GEMM into buf1
        gemm_bias<<<dim3(HID_ / 64, M_ / 128), 256, 0, stream>>>(
            buf, nullptr, W_ih1, b_ih1, b_hh1, buf1, M_, HID_, HID_);
        l1buf = buf1;
    } else {
        // 3b) fallback: chunk through d_out (ex region dead until next scan)
        for (int c = 0; c < 16; ++c) {
            const float* Ac = buf + (size_t)c * 1024 * HID_;
            gemm_bias<<<dim3(HID_ / 64, 1024 / 128), 256, 0, stream>>>(
                Ac, nullptr, W_ih1, b_ih1, b_hh1, tmp, 1024, HID_, HID_);
            copy4<<<1024, 256, 0, stream>>>(
                (const float4*)tmp, (float4*)(buf + (size_t)c * 1024 * HID_),
                1024 * HID_ / 4);
        }
        l1buf = buf;
    }

    // 4) layer-1 scan (tags 513..1024; stale/garbage high words never match)
    rnn_scan_tag<<<256, 512, scan_lds, stream>>>(W_hh1, l1buf, ex, 513u);

    // 5) out = h1 @ W_out^T + b_out (fully rewrites d_out incl. ex region)
    gemm_bias<<<dim3(LAB_ / 64, M_ / 128), 256, 0, stream>>>(
        l1buf, nullptr, W_out, b_out, nullptr, out, M_, HID_, LAB_);
}

// Round 5
// 3948.920 us; speedup vs baseline: 75.0651x; 75.0651x over previous
//
#include <hip/hip_runtime.h>
#include <math.h>

#define B_    32
#define S_    512
#define EMB_  512
#define HID_  1024
#define LAB_  64
#define M_    (B_ * S_)

// ---------------------------------------------------------------------------
// R14 exchange: single-hop EPOCH-BIT words, depth-4 slots, no poison stores.
//   word = u64 {enc(h[b0,n]) lo, enc(h[b1,n]) hi},
//   enc(h) = bits(h) | (e<<30) where e = (t>>2)&1.
//   layout [4 slots][16 groups][1024 neurons] u64 = 512 KB in d_out.
//
// Why bit 30: tanh output has |h| <= 1 -> biased exponent <= 127 -> bit 30
// of the fp32 encoding is ALWAYS 0. The producer ORs in the epoch bit; the
// consumer accepts a word iff BOTH dwords carry the expected epoch, then
// masks bit 30 off (exact decode, no rounding). Per-dword check also makes
// any tearing concern moot (8B atomic store anyway).
//
// Slot-reuse safety (no consumer stores, no cross-address ordering):
//   skew bound: staging step t requires publish(t-1) from EVERY WG of the
//   group (barrier orders each WG's slot-reads before its publishes), so
//   producers run at most 1 step ahead of the slowest consumer. Hence when
//   a consumer awaits data(t) in slot t&3, the only other value that can
//   ever occupy that slot is data(t-4) -- opposite epoch -> rejected.
//   data(t+4)/data(t+8) cannot exist yet (would need publish(t+2)+ from
//   the waiting WG itself). ABA is structurally closed; R13's poison-store
//   ordering window is gone, and publish traffic halves.
//   Startup: NaN pre-fill (bit30=1) is rejected by the first, epoch-0,
//   read of each slot; afterwards each poll address's accepted epoch-0
//   value is coherence-ordered past the fill (same reader thread), so the
//   fill can never satisfy an epoch-1 check.
//
// History: R9 tagged/depth-2 agent = 7900 cyc/step (congestion+RT bound).
// R10 __ATOMIC_RELEASE = buffer_wbl2/step, 6x worse. R11 flag hop = +2 RT
// on the serial chain, 1.5x worse. R12 plain-store/sc0-load L2 exchange =
// coherence pathology, 130x worse. Agent-scope single-hop self-validating
// words is the proven shape; R14 halves its polled bytes AND its publish
// stores.
// ---------------------------------------------------------------------------
#define EXS_STRIDE (16 * 1024)            // u64 per slot (16 groups x 1024)
#define NANPAT64   0x7FC000007FC00000ULL  // bit30 set in both dwords
#define EPMASK64   0x4000000040000000ULL  // bit30 of both dwords
#define PAYMASK    0xBFFFFFFFu            // clears bit 30

__device__ __forceinline__ unsigned long long aload64(const unsigned long long* p) {
    return __hip_atomic_load((unsigned long long*)p, __ATOMIC_RELAXED,
                             __HIP_MEMORY_SCOPE_AGENT);
}
__device__ __forceinline__ void astore64(unsigned long long* p, unsigned long long v) {
    __hip_atomic_store(p, v, __ATOMIC_RELAXED, __HIP_MEMORY_SCOPE_AGENT);
}

// ---------------------------------------------------------------------------
// fp32 tiled GEMM, BM=128, BN=64, BK=16, 256 threads, 8x4/thread (measured
// ~0.79 ms total across the three projections). Optional row-gather on A.
// ---------------------------------------------------------------------------
__global__ __launch_bounds__(256) void gemm_bias(
    const float* __restrict__ A, const int* __restrict__ tokens,
    const float* __restrict__ W, const float* __restrict__ bias,
    const float* __restrict__ bias2, float* __restrict__ C,
    int M, int K, int N)
{
    __shared__ float As[128][17];
    __shared__ float Ws[64][17];

    const int tid = threadIdx.x;
    const int tx  = tid & 15;
    const int ty  = tid >> 4;
    const int n0  = blockIdx.x * 64;
    const int m0  = blockIdx.y * 128;

    const int lr  = tid >> 2;
    const int lk  = (tid & 3) << 2;

    const int ar0 = tokens ? tokens[m0 + lr]      : (m0 + lr);
    const int ar1 = tokens ? tokens[m0 + 64 + lr] : (m0 + 64 + lr);
    const float* __restrict__ arow0 = A + (size_t)ar0 * K;
    const float* __restrict__ arow1 = A + (size_t)ar1 * K;
    const float* __restrict__ wrow  = W + (size_t)(n0 + lr) * K;

    float bs[4];
#pragma unroll
    for (int j = 0; j < 4; ++j) {
        int n = n0 + tx * 4 + j;
        bs[j] = bias[n] + (bias2 ? bias2[n] : 0.0f);
    }

    float acc[8][4] = {};

    for (int k0 = 0; k0 < K; k0 += 16) {
        const float4 a0 = *(const float4*)(arow0 + k0 + lk);
        const float4 a1 = *(const float4*)(arow1 + k0 + lk);
        const float4 wv = *(const float4*)(wrow  + k0 + lk);
        __syncthreads();
        As[lr][lk + 0] = a0.x; As[lr][lk + 1] = a0.y;
        As[lr][lk + 2] = a0.z; As[lr][lk + 3] = a0.w;
        As[64 + lr][lk + 0] = a1.x; As[64 + lr][lk + 1] = a1.y;
        As[64 + lr][lk + 2] = a1.z; As[64 + lr][lk + 3] = a1.w;
        Ws[lr][lk + 0] = wv.x; Ws[lr][lk + 1] = wv.y;
        Ws[lr][lk + 2] = wv.z; Ws[lr][lk + 3] = wv.w;
        __syncthreads();

#pragma unroll
        for (int kk = 0; kk < 16; ++kk) {
            float b[4], a[8];
#pragma unroll
            for (int j = 0; j < 4; ++j) b[j] = Ws[tx * 4 + j][kk];
#pragma unroll
            for (int i = 0; i < 8; ++i) a[i] = As[ty * 8 + i][kk];
#pragma unroll
            for (int i = 0; i < 8; ++i)
#pragma unroll
                for (int j = 0; j < 4; ++j)
                    acc[i][j] += a[i] * b[j];
        }
    }

#pragma unroll
    for (int i = 0; i < 8; ++i) {
        const int m = m0 + ty * 8 + i;
        float4 v;
        v.x = acc[i][0] + bs[0];
        v.y = acc[i][1] + bs[1];
        v.z = acc[i][2] + bs[2];
        v.w = acc[i][3] + bs[3];
        *(float4*)(C + (size_t)m * N + n0 + tx * 4) = v;
    }
}

// ---------------------------------------------------------------------------
// Poison-fill: pre-sentinel the exchange region (65536 u64 = 512 KB) with
// bit30-set words. Kernel-boundary release makes it visible to agent loads.
// ---------------------------------------------------------------------------
__global__ __launch_bounds__(256) void fill_poison(unsigned long long* p, int n)
{
    const int i = blockIdx.x * 256 + threadIdx.x;
    if (i < n) p[i] = NANPAT64;
}

// ---------------------------------------------------------------------------
// Weight-stationary persistent scan, R14: epoch-bit exchange (see header).
// 256 WGs x 512 threads, 1 WG/CU. Group = wg&15 (16 groups x 2 batches).
// Slice s = wg>>4: 64 neurons. Weights in registers: 8 neurons x 16
// strided k = 128 VGPRs. LDS h: float2[2][1024] double-buffered -> ONE
// barrier per step. Safety: a thread's reads of buf[(t-1)&1] precede
// (program order) its staging of buf[t&1], which precedes barrier_t; any
// thread writes buf[(t+1)&1] = buf[(t-1)&1] only after passing barrier_t.
// 16-acc halving-tree reduction: lane p holds out(p&15) at the end.
// ---------------------------------------------------------------------------
__global__ __launch_bounds__(512, 2) void rnn_scan_ep(
    const float* __restrict__ Whh,          // [H][H] row-major
    float* __restrict__ x,                  // [B,S,H]  xp in, h out (in place)
    unsigned long long* __restrict__ ex)    // epoch exchange (d_out)
{
    extern __shared__ float smem[];
    float2* hb2 = (float2*)smem;            // [2][1024] float2 = 16 KB

    const int wg  = blockIdx.x;
    const int bg  = wg & 15;         // batch group (2 batches)
    const int s   = wg >> 4;         // slice 0..15 (64 neurons)
    const int tid = threadIdx.x;     // 0..511
    const int j8  = tid >> 6;        // wave 0..7 -> neurons s*64 + j8*8 ..+7
    const int kg  = tid & 63;        // lane; k = kg + 64q
    const int b0  = bg * 2;

    // weights: 8 neurons x 16 strided k = 128 VGPRs (lane-coalesced loads)
    float wreg[8][16];
    {
        const float* wb = Whh + (size_t)(s * 64 + j8 * 8) * HID_ + kg;
#pragma unroll
        for (int i = 0; i < 8; ++i)
#pragma unroll
            for (int q = 0; q < 16; ++q)
                wreg[i][q] = wb[(size_t)i * HID_ + q * 64];
    }

    const int oi = (kg >> 1) & 7, ob = kg & 1;     // lane's output (kg<16)
    const int ok = s * 64 + j8 * 8 + oi;           // neuron index

    // group-local exchange base (this group's 1024 words within each slot)
    unsigned long long* const exg = ex + (size_t)bg * 1024;

    // consumer word indices: neurons 2*tid, 2*tid+1 (contiguous pair)
    const int cn = tid * 2;

    // incremental xp/h pointer (kg<16 lanes only)
    float* px = x + (size_t)(b0 + ob) * S_ * HID_ + ok;

    for (int t = 0; t < S_; ++t) {
        float2* cur = hb2 + (size_t)(t & 1) * HID_;

        // ---- xp prefetch: independent of h, overlaps the poll ----
        float xpv = 0.f;
        if (kg < 16) xpv = *px;

        // ---- stage h_{t-1}: epoch-checked poll on 2 contiguous words ----
        if (t > 0) {
            const unsigned e = ((unsigned)(t - 1) >> 2) & 1u;
            const unsigned long long want = e ? EPMASK64 : 0ULL;
            const unsigned long long* exs =
                exg + (size_t)((t - 1) & 3) * EXS_STRIDE;
            unsigned long long u0 = 0, u1 = 0;
            unsigned pend = 3u;
            do {
                if (pend & 1u) {
                    u0 = aload64(exs + cn);
                    if ((u0 & EPMASK64) == want) pend &= ~1u;
                }
                if (pend & 2u) {
                    u1 = aload64(exs + cn + 1);
                    if ((u1 & EPMASK64) == want) pend &= ~2u;
                }
            } while (pend);
            float4 v;
            v.x = __uint_as_float((unsigned)u0 & PAYMASK);          // h[b0,cn]
            v.y = __uint_as_float((unsigned)(u0 >> 32) & PAYMASK);  // h[b1,cn]
            v.z = __uint_as_float((unsigned)u1 & PAYMASK);          // h[b0,cn+1]
            v.w = __uint_as_float((unsigned)(u1 >> 32) & PAYMASK);  // h[b1,cn+1]
            *(float4*)&cur[cn] = v;      // 16B contiguous: conflict-free
        } else {
            *(float4*)&cur[cn] = make_float4(0.f, 0.f, 0.f, 0.f);
        }
        __syncthreads();   // the ONE barrier: staging done -> compute reads

        // ---- partials: v[a], a = i*2+b, over 16 strided k ----
        float v[16] = {};
#pragma unroll
        for (int q = 0; q < 16; ++q) {
            const float2 hv = cur[kg + 64 * q];    // lane-contig b64: free
#pragma unroll
            for (int i = 0; i < 8; ++i) {
                const float w = wreg[i][q];
                v[i * 2 + 0] += w * hv.x;
                v[i * 2 + 1] += w * hv.y;
            }
        }

        // ---- halving-tree reduction: 15+2 shfls fold 16 accs -> 1 ----
#pragma unroll
        for (int st = 0; st < 4; ++st) {
            const int m  = 1 << st;
            const int nh = 8 >> st;
            const bool hi = (kg & m) != 0;
#pragma unroll
            for (int j = 0; j < 8; ++j) {
                if (j < nh) {
                    const float a0 = v[2 * j], a1 = v[2 * j + 1];
                    const float got = __shfl_xor(hi ? a0 : a1, m, 64);
                    v[j] = (hi ? a1 : a0) + got;
                }
            }
        }
        v[0] += __shfl_xor(v[0], 16, 64);
        v[0] += __shfl_xor(v[0], 32, 64);
        // lane p now holds out(p & 15), a = i*2+b

        // ---- publish one epoch-stamped pair-packed word per even lane ----
        float hv = 0.f;
        if (kg < 16) {
            hv = tanhf(xpv + v[0]);
            *px = hv;                   // for the next-layer GEMM
            px += HID_;
        }
        const float hvp = __shfl_xor(hv, 1, 64);   // partner batch, same neuron
        if (kg < 16 && (kg & 1) == 0) {
            const unsigned eb = (((unsigned)t >> 2) & 1u) << 30;
            // even lane: ob=0 -> low dword = batch b0, high = batch b1
            const unsigned long long u =
                ((unsigned long long)(__float_as_uint(hvp) | eb) << 32) |
                (unsigned long long)(__float_as_uint(hv) | eb);
            astore64(exg + (size_t)(t & 3) * EXS_STRIDE + ok, u);
        }
        // no trailing barrier: double-buffered hb2 (see header comment)
    }
}

__global__ __launch_bounds__(256) void copy4(
    const float4* __restrict__ src, float4* __restrict__ dst, int n4)
{
    const int i = blockIdx.x * 256 + threadIdx.x;
    if (i < n4) dst[i] = src[i];
}

extern "C" void kernel_launch(void* const* d_in, const int* in_sizes, int n_in,
                              void* d_out, int out_size, void* d_ws, size_t ws_size,
                              hipStream_t stream)
{
    const int*   tokens = (const int*)  d_in[0];
    const float* emb    = (const float*)d_in[1];
    const float* W_ih0  = (const float*)d_in[2];
    const float* W_hh0  = (const float*)d_in[3];
    const float* b_ih0  = (const float*)d_in[4];
    const float* b_hh0  = (const float*)d_in[5];
    const float* W_ih1  = (const float*)d_in[6];
    const float* W_hh1  = (const float*)d_in[7];
    const float* b_ih1  = (const float*)d_in[8];
    const float* b_hh1  = (const float*)d_in[9];
    const float* W_out  = (const float*)d_in[10];
    const float* b_out  = (const float*)d_in[11];
    float* out = (float*)d_out;

    const size_t BUF = (size_t)B_ * S_ * HID_;   // 64 MiB
    float* buf  = (float*)d_ws;
    float* buf1 = buf + BUF;                     // only if ws_size permits
    float* tmp  = (float*)d_out;                 // chunk bounce (fallback)
    unsigned long long* ex = (unsigned long long*)d_out;  // 512 KB exchange
    const int EXN = 4 * EXS_STRIDE;              // 65536 u64

    const int two_buf = (ws_size >= 2 * BUF * sizeof(float));  // constant/call

    // 96 KB dynamic LDS -> exactly 1 WG/CU (256 WGs co-resident on 256 CUs)
    const size_t scan_lds = 98304;
    hipFuncSetAttribute((const void*)rnn_scan_ep,
                        hipFuncAttributeMaxDynamicSharedMemorySize, (int)scan_lds);

    // 1) xp0 = gather(emb,tokens) @ W_ih0^T + b_ih0 + b_hh0  -> buf
    gemm_bias<<<dim3(HID_ / 64, M_ / 128), 256, 0, stream>>>(
        emb, tokens, W_ih0, b_ih0, b_hh0, buf, M_, EMB_, HID_);

    // 2) layer-0 scan (in place on buf); exchange pre-filled with bit30 set
    fill_poison<<<EXN / 256, 256, 0, stream>>>(ex, EXN);
    rnn_scan_ep<<<256, 512, scan_lds, stream>>>(W_hh0, buf, ex);

    float* l1buf;
    if (two_buf) {
        // 3a) full-grid xp1 GEMM into buf1
        gemm_bias<<<dim3(HID_ / 64, M_ / 128), 256, 0, stream>>>(
            buf, nullptr, W_ih1, b_ih1, b_hh1, buf1, M_, HID_, HID_);
        l1buf = buf1;
    } else {
        // 3b) fallback: chunk through d_out (ex region dead until refill)
        for (int c = 0; c < 16; ++c) {
            const float* Ac = buf + (size_t)c * 1024 * HID_;
            gemm_bias<<<dim3(HID_ / 64, 1024 / 128), 256, 0, stream>>>(
                Ac, nullptr, W_ih1, b_ih1, b_hh1, tmp, 1024, HID_, HID_);
            copy4<<<1024, 256, 0, stream>>>(
                (const float4*)tmp, (float4*)(buf + (size_t)c * 1024 * HID_),
                1024 * HID_ / 4);
        }
        l1buf = buf;
    }

    // 4) layer-1 scan; refill first (scan0 leftovers carry epoch bits)
    fill_poison<<<EXN / 256, 256, 0, stream>>>(ex, EXN);
    rnn_scan_ep<<<256, 512, scan_lds, stream>>>(W_hh1, l1buf, ex);

    // 5) out = h1 @ W_out^T + b_out (fully rewrites d_out incl. ex region)
    gemm_bias<<<dim3(LAB_ / 64, M_ / 128), 256, 0, stream>>>(
        l1buf, nullptr, W_out, b_out, nullptr, out, M_, HID_, LAB_);
}